// Round 11
// baseline (124.222 us; speedup 1.0000x reference)
//
#include <hip/hip_runtime.h>

// Problem constants (reference: B,T,D,O = 16,1024,1024,10; T==D required)
#define BB 16
#define TT 1024
#define DD 1024
#define OO 10

// ---------------------------------------------------------------------------
// Two kernels, K2 eliminated algebraically (max-free softmax), R10 structure.
//   K1: u[b,o,t] = exp((X[b,t,:].W[o,:] + b_o)/10); Z[b,o] = sum_t u
//       (scores have sd~0.064 -> exp safe without max-subtraction; u/Z is
//        exactly reference softmax).
//   K3: out[b,o,t] = (X[b,t,:].u[b,:,o]) / Z[b,o]  (normalizer factors out).
//
// Gemm body = R5's proven mapping: grid (T/32, B), 4 waves, 32 rows/block;
// operand (W or u-slab) in LDS [o][t4] read as 8-address broadcast float4;
// lane = g*8+l of wave w: group g owns rows t0+g+8j, slice l owns
// d = w*256+it*32+l*4; 2-deep x prefetch; 8-lane dots + LDS combine.
//
// R11 change (single variable): X loads are NON-TEMPORAL (L1 bypass).
// Theory: each X-load instruction touches 8 rows 4096 B apart -> L1 set
// index bits [11:6] identical -> 8+ lines per set in a ~8-way 32 KB L1 ->
// conflict evictions + MSHR serialization (explains R8 phase C not speeding
// up despite IC-warm X). X has ZERO reuse, so L1 caching is pure overhead.
// W/u staging (32x reuse across blocks) and stores stay normally cached.
//
// Lessons kept: no occupancy-hint launch_bounds (R2 spill), unroll-1 outer +
// 2-deep manual prefetch (R9: depth-4 regressed), no per-chunk barriers (R6),
// no device-barrier fusion (R8), no per-block softmax fold (R9).
// ---------------------------------------------------------------------------

typedef float f32x4 __attribute__((ext_vector_type(4)));

__device__ __forceinline__ float4 ntload4(const float* p) {
    f32x4 v = __builtin_nontemporal_load((const f32x4*)p);
    return make_float4(v.x, v.y, v.z, v.w);
}

template <bool FIRST>
__global__ __launch_bounds__(256) void gemm10_kernel(
    const float* __restrict__ X,     // (B,T,D) logits
    const float* __restrict__ Wt,    // FIRST: W (O,D); else u (B,O,T)
    const float* __restrict__ bias,  // FIRST only
    float* __restrict__ Y,           // FIRST: u (B,O,T); else out (B,O,T)
    float* __restrict__ Z)           // (B,O): FIRST accumulates, else reads
{
    __shared__ float4 sW4[OO * 256];    // 40 KB operand ([o][t4])
    __shared__ float  part[4][32][OO];  // 5 KB
    __shared__ float  uv[32][OO];       // 1.25 KB (K1 epilogue reduce)

    const int b   = blockIdx.y;
    const int t0  = blockIdx.x * 32;
    const int tid = threadIdx.x;

    // ---- stage operand -> LDS (2560 float4, contiguous, coalesced) ----
    {
        const float4* src = (const float4*)(Wt + (FIRST ? 0 : (size_t)b * OO * TT));
#pragma unroll
        for (int c = 0; c < 10; ++c)
            sW4[c * 256 + tid] = src[c * 256 + tid];
    }
    __syncthreads();

    const int w    = tid >> 6;       // wave 0..3 -> d quarter
    const int lane = tid & 63;
    const int l    = lane & 7;       // d-slice within row
    const int g    = lane >> 3;      // row group 0..7
    const int dofs = w * 256 + l * 4;

    const float* xp[4];
#pragma unroll
    for (int j = 0; j < 4; ++j)
        xp[j] = X + ((size_t)b * TT + t0 + g + 8 * j) * DD + dofs;
    const float* sWl = (const float*)sW4 + dofs;

    float acc[4][OO];
#pragma unroll
    for (int j = 0; j < 4; ++j)
#pragma unroll
        for (int o = 0; o < OO; ++o) acc[j][o] = 0.f;

    // 2-deep prefetch of the logits slices (non-temporal: L1 bypass)
    float4 x0[4], x1[4];
#pragma unroll
    for (int j = 0; j < 4; ++j) {
        x0[j] = ntload4(xp[j]);
        x1[j] = ntload4(xp[j] + 32);
    }

#pragma unroll 1
    for (int it = 0; it < 8; it += 2) {
        float4 c0[4];
#pragma unroll
        for (int j = 0; j < 4; ++j) c0[j] = x0[j];
        if (it < 6) {
#pragma unroll
            for (int j = 0; j < 4; ++j)
                x0[j] = ntload4(xp[j] + (it + 2) * 32);
        }
        {
            const float* wp = sWl + it * 32;
#pragma unroll
            for (int o = 0; o < OO; ++o) {
                const float4 wv = *(const float4*)(wp + o * DD);
#pragma unroll
                for (int j = 0; j < 4; ++j)
                    acc[j][o] += c0[j].x * wv.x + c0[j].y * wv.y +
                                 c0[j].z * wv.z + c0[j].w * wv.w;
            }
        }
#pragma unroll
        for (int j = 0; j < 4; ++j) c0[j] = x1[j];
        if (it < 5) {
#pragma unroll
            for (int j = 0; j < 4; ++j)
                x1[j] = ntload4(xp[j] + (it + 3) * 32);
        }
        {
            const float* wp = sWl + (it + 1) * 32;
#pragma unroll
            for (int o = 0; o < OO; ++o) {
                const float4 wv = *(const float4*)(wp + o * DD);
#pragma unroll
                for (int j = 0; j < 4; ++j)
                    acc[j][o] += c0[j].x * wv.x + c0[j].y * wv.y +
                                 c0[j].z * wv.z + c0[j].w * wv.w;
            }
        }
    }

    // 3-level reduction within each 8-lane group, then cross-wave via LDS.
#pragma unroll
    for (int j = 0; j < 4; ++j) {
#pragma unroll
        for (int o = 0; o < OO; ++o) {
            float v = acc[j][o];
            v += __shfl_down(v, 4, 8);
            v += __shfl_down(v, 2, 8);
            v += __shfl_down(v, 1, 8);
            if (l == 0) part[w][j * 8 + g][o] = v;
        }
    }
    __syncthreads();

    // 32 rows x 10 o = 320 outputs
    for (int idx = tid; idx < 32 * OO; idx += 256) {
        const int row = idx / OO;
        const int o   = idx % OO;
        float v = part[0][row][o] + part[1][row][o] +
                  part[2][row][o] + part[3][row][o];
        if (FIRST) {
            // u = exp((dot + bias)/O); |arg| < ~0.5 -> max-free exp is safe
            float u = __expf((v + bias[o]) * (1.0f / OO));
            Y[((size_t)b * OO + o) * TT + (t0 + row)] = u;
            uv[row][o] = u;
        } else {
            const float invZ = 1.0f / Z[b * OO + o];
            Y[((size_t)b * OO + o) * TT + (t0 + row)] = v * invZ;
        }
    }

    if (FIRST) {
        __syncthreads();
        if (tid < OO) {
            float s = 0.f;
#pragma unroll
            for (int row = 0; row < 32; ++row) s += uv[row][tid];
            atomicAdd(&Z[b * OO + tid], s);   // device-scope by default
        }
    }
}

extern "C" void kernel_launch(void* const* d_in, const int* in_sizes, int n_in,
                              void* d_out, int out_size, void* d_ws, size_t ws_size,
                              hipStream_t stream)
{
    const float* logits = (const float*)d_in[0];
    // d_in[1] = decision — unused by the forward math
    const float* W    = (const float*)d_in[2];
    const float* bias = (const float*)d_in[3];
    float* out = (float*)d_out;

    float* u = (float*)d_ws;                         // B*O*T floats = 2.62 MB
    float* Z = (float*)((char*)d_ws + (4 << 20));    // B*O floats = 640 B

    // ws is poisoned 0xAA before every call -> zero the Z accumulators
    (void)hipMemsetAsync(Z, 0, BB * OO * sizeof(float), stream);

    dim3 grid(TT / 32, BB);
    // K1: u = exp((X.W^T + b)/O), Z = sum_t u   (kernel boundary = fence)
    gemm10_kernel<true><<<grid, 256, 0, stream>>>(logits, W, bias, u, Z);
    // K3: out = (X . u) * (1/Z)
    gemm10_kernel<false><<<grid, 256, 0, stream>>>(logits, u, nullptr, out, Z);
}